// Round 1
// baseline (1266.799 us; speedup 1.0000x reference)
//
#include <hip/hip_runtime.h>
#include <hip/hip_bf16.h>

#define B 2
#define S 8192
#define H 16
#define D 64
#define NB 32          // S / BS
#define BS 256
#define SAMP 256
#define BH (B*H)
#define BHS (B*H*S)
#define SCALE 0.125f   // 1/sqrt(64)
#define LOG_S_OVER_SAMP 3.4657359027997265f  // log(8192/256) = log(32)

// ---------------------------------------------------------------------------
// Kernel 1: LSH hash of Q and K.  hash = gray(bin) = bin ^ (bin>>1)
// grid = BH * (S/256), block = 256; thread -> one (b,h,s) row of Q and K.
// ---------------------------------------------------------------------------
__global__ __launch_bounds__(256) void k_hash(const float* __restrict__ q,
                                              const float* __restrict__ k,
                                              const float* __restrict__ pd,
                                              int* __restrict__ hq,
                                              int* __restrict__ hk) {
    __shared__ float spd[D * 8];
    const int t = threadIdx.x;
    for (int i = t; i < D * 8; i += 256) spd[i] = pd[i];
    __syncthreads();

    const int sc = blockIdx.x & (NB - 1);      // S/256 == 32 chunks
    const int bh = blockIdx.x >> 5;
    const int s  = sc * 256 + t;
    const int h  = bh & (H - 1), b = bh >> 4;

    const long long rowoff = (((long long)(b * S + s)) * H + h) * (long long)D;
    const float4* q4 = (const float4*)(q + rowoff);
    const float4* k4 = (const float4*)(k + rowoff);

    float dq[8], dk[8];
#pragma unroll
    for (int p = 0; p < 8; ++p) { dq[p] = 0.f; dk[p] = 0.f; }

#pragma unroll
    for (int i = 0; i < 16; ++i) {
        float4 xq = q4[i];
        float4 xk = k4[i];
#pragma unroll
        for (int p = 0; p < 8; ++p) {
            dq[p] += xq.x * spd[(4*i+0)*8+p] + xq.y * spd[(4*i+1)*8+p]
                   + xq.z * spd[(4*i+2)*8+p] + xq.w * spd[(4*i+3)*8+p];
            dk[p] += xk.x * spd[(4*i+0)*8+p] + xk.y * spd[(4*i+1)*8+p]
                   + xk.z * spd[(4*i+2)*8+p] + xk.w * spd[(4*i+3)*8+p];
        }
    }
    int bq = 0, bk = 0;
#pragma unroll
    for (int p = 0; p < 8; ++p) {
        bq |= (dq[p] > 0.f) ? (1 << p) : 0;
        bk |= (dk[p] > 0.f) ? (1 << p) : 0;
    }
    hq[(long long)bh * S + s] = bq ^ (bq >> 1);
    hk[(long long)bh * S + s] = bk ^ (bk >> 1);
}

// ---------------------------------------------------------------------------
// Kernel 2: stable counting sort (argsort) of hashes per (b,h).
// grid = 2*BH (first BH blocks sort hq->qs, next BH sort hk->ks), block = 64.
// ---------------------------------------------------------------------------
#define SORT_NT 64
#define SORT_CH (S / SORT_NT)   // 128

__global__ __launch_bounds__(SORT_NT) void k_sort(const int* __restrict__ hq,
                                                  const int* __restrict__ hk,
                                                  int* __restrict__ qs,
                                                  int* __restrict__ ks) {
    __shared__ int hist[SORT_NT * 256];
    __shared__ int base[257];
    const int t  = threadIdx.x;
    const int bh = blockIdx.x & (BH - 1);
    const bool isQ = blockIdx.x < BH;
    const int* hp = (isQ ? hq : hk) + (long long)bh * S;
    int*       sp = (isQ ? qs : ks) + (long long)bh * S;

    for (int i = 0; i < 256; ++i) hist[t * 256 + i] = 0;
    __syncthreads();
    for (int i = 0; i < SORT_CH; ++i) hist[t * 256 + hp[t * SORT_CH + i]]++;
    __syncthreads();

    // per-bin totals (4 bins per thread)
    for (int bi = 0; bi < 4; ++bi) {
        const int bin = t * 4 + bi;
        int sum = 0;
        for (int tt = 0; tt < SORT_NT; ++tt) sum += hist[tt * 256 + bin];
        base[bin + 1] = sum;
    }
    __syncthreads();
    if (t == 0) {
        base[0] = 0;
        for (int i = 1; i <= 256; ++i) base[i] += base[i - 1];
    }
    __syncthreads();

    // convert per-thread counts into per-thread starting offsets (stable)
    for (int bi = 0; bi < 4; ++bi) {
        const int bin = t * 4 + bi;
        int run = base[bin];
        for (int tt = 0; tt < SORT_NT; ++tt) {
            int c = hist[tt * 256 + bin];
            hist[tt * 256 + bin] = run;
            run += c;
        }
    }
    __syncthreads();

    // stable scatter: thread t owns contiguous s range, emits in order
    for (int i = 0; i < SORT_CH; ++i) {
        const int s0  = t * SORT_CH + i;
        const int bin = hp[s0];
        sp[hist[t * 256 + bin]++] = s0;
    }
}

// ---------------------------------------------------------------------------
// Kernel 3: block-diagonal attention in sorted order; output scattered back
// to ORIGINAL query order (so no inverse permutation pass needed).
// grid = BH*NB, block = 256 (one thread = one query row).
// ---------------------------------------------------------------------------
__global__ __launch_bounds__(256) void k_blk(const float* __restrict__ q,
                                             const float* __restrict__ k,
                                             const float* __restrict__ v,
                                             const int* __restrict__ qs,
                                             const int* __restrict__ ks,
                                             float* __restrict__ ablk,
                                             float* __restrict__ lseblk) {
    __shared__ float kt[BS][D];
    __shared__ float vt[BS][D];
    const int t   = threadIdx.x;
    const int blk = blockIdx.x & (NB - 1);
    const int bh  = blockIdx.x >> 5;
    const int h   = bh & (H - 1), b = bh >> 4;

    const long long sbase = (long long)bh * S + (long long)blk * BS;
    const int krow = ks[sbase + t];
    const int qrow = qs[sbase + t];

    const float4* k4 = (const float4*)(k + (((long long)(b * S + krow)) * H + h) * D);
    const float4* v4 = (const float4*)(v + (((long long)(b * S + krow)) * H + h) * D);
    float4* kt4 = (float4*)kt[t];
    float4* vt4 = (float4*)vt[t];
#pragma unroll
    for (int i = 0; i < 16; ++i) { kt4[i] = k4[i]; vt4[i] = v4[i]; }

    float qreg[64];
    const float4* q4 = (const float4*)(q + (((long long)(b * S + qrow)) * H + h) * D);
#pragma unroll
    for (int i = 0; i < 16; ++i) ((float4*)qreg)[i] = q4[i];
    __syncthreads();

    float m = -1e30f, l = 0.f;
    float acc[64];
#pragma unroll
    for (int d = 0; d < 64; ++d) acc[d] = 0.f;

    for (int j = 0; j < BS; ++j) {
        float s0 = 0.f, s1 = 0.f, s2 = 0.f, s3 = 0.f;
#pragma unroll
        for (int d = 0; d < 64; d += 4) {
            s0 += qreg[d + 0] * kt[j][d + 0];
            s1 += qreg[d + 1] * kt[j][d + 1];
            s2 += qreg[d + 2] * kt[j][d + 2];
            s3 += qreg[d + 3] * kt[j][d + 3];
        }
        const float sd = ((s0 + s1) + (s2 + s3)) * SCALE;
        const float mn  = fmaxf(m, sd);
        const float scl = __expf(m - mn);
        const float p   = __expf(sd - mn);
        l = l * scl + p;
#pragma unroll
        for (int d = 0; d < 64; ++d) acc[d] = acc[d] * scl + p * vt[j][d];
        m = mn;
    }

    const float inv = 1.f / l;
    const float lse = m + __logf(l);
    const long long obase = (((long long)(b * S + qrow)) * H + h) * D;
    float4* op = (float4*)(ablk + obase);
#pragma unroll
    for (int i = 0; i < 16; ++i) {
        float4 o;
        o.x = acc[4 * i + 0] * inv;
        o.y = acc[4 * i + 1] * inv;
        o.z = acc[4 * i + 2] * inv;
        o.w = acc[4 * i + 3] * inv;
        op[i] = o;
    }
    lseblk[((long long)(b * S + qrow)) * H + h] = lse;
}

// ---------------------------------------------------------------------------
// Kernel 4: residual sampled-key attention + logaddexp combine (fused).
// grid = BH*NB (32 chunks of 256 queries each), block = 256.
// ---------------------------------------------------------------------------
__global__ __launch_bounds__(256) void k_res(const float* __restrict__ q,
                                             const float* __restrict__ k,
                                             const float* __restrict__ v,
                                             const int* __restrict__ sidx,
                                             const float* __restrict__ ablk,
                                             const float* __restrict__ lseblk,
                                             float* __restrict__ out) {
    __shared__ float kt[SAMP][D];
    __shared__ float vt[SAMP][D];
    const int t     = threadIdx.x;
    const int chunk = blockIdx.x & (NB - 1);
    const int bh    = blockIdx.x >> 5;
    const int h     = bh & (H - 1), b = bh >> 4;

    const int krow = sidx[(long long)bh * SAMP + t];
    const float4* k4 = (const float4*)(k + (((long long)(b * S + krow)) * H + h) * D);
    const float4* v4 = (const float4*)(v + (((long long)(b * S + krow)) * H + h) * D);
    float4* kt4 = (float4*)kt[t];
    float4* vt4 = (float4*)vt[t];
#pragma unroll
    for (int i = 0; i < 16; ++i) { kt4[i] = k4[i]; vt4[i] = v4[i]; }

    const int s = chunk * 256 + t;
    float qreg[64];
    const float4* q4 = (const float4*)(q + (((long long)(b * S + s)) * H + h) * D);
#pragma unroll
    for (int i = 0; i < 16; ++i) ((float4*)qreg)[i] = q4[i];
    __syncthreads();

    float m = -1e30f, l = 0.f;
    float acc[64];
#pragma unroll
    for (int d = 0; d < 64; ++d) acc[d] = 0.f;

    for (int j = 0; j < SAMP; ++j) {
        float s0 = 0.f, s1 = 0.f, s2 = 0.f, s3 = 0.f;
#pragma unroll
        for (int d = 0; d < 64; d += 4) {
            s0 += qreg[d + 0] * kt[j][d + 0];
            s1 += qreg[d + 1] * kt[j][d + 1];
            s2 += qreg[d + 2] * kt[j][d + 2];
            s3 += qreg[d + 3] * kt[j][d + 3];
        }
        const float sd = ((s0 + s1) + (s2 + s3)) * SCALE;
        const float mn  = fmaxf(m, sd);
        const float scl = __expf(m - mn);
        const float p   = __expf(sd - mn);
        l = l * scl + p;
#pragma unroll
        for (int d = 0; d < 64; ++d) acc[d] = acc[d] * scl + p * vt[j][d];
        m = mn;
    }

    const float lr = m + __logf(l) + LOG_S_OVER_SAMP;
    const float lb = lseblk[((long long)(b * S + s)) * H + h];
    const float mx = fmaxf(lb, lr);
    const float lt = mx + __logf(__expf(lb - mx) + __expf(lr - mx));
    const float wb = __expf(lb - lt);
    const float wr = __expf(lr - lt) / l;   // folds the softmax normalize of a_r

    const long long obase = (((long long)(b * S + s)) * H + h) * D;
    const float4* ab4 = (const float4*)(ablk + obase);
    float4* o4 = (float4*)(out + obase);
#pragma unroll
    for (int i = 0; i < 16; ++i) {
        float4 a = ab4[i];
        float4 o;
        o.x = a.x * wb + acc[4 * i + 0] * wr;
        o.y = a.y * wb + acc[4 * i + 1] * wr;
        o.z = a.z * wb + acc[4 * i + 2] * wr;
        o.w = a.w * wb + acc[4 * i + 3] * wr;
        o4[i] = o;
    }
}

// ---------------------------------------------------------------------------
extern "C" void kernel_launch(void* const* d_in, const int* in_sizes, int n_in,
                              void* d_out, int out_size, void* d_ws, size_t ws_size,
                              hipStream_t stream) {
    const float* q   = (const float*)d_in[0];
    const float* k   = (const float*)d_in[1];
    const float* v   = (const float*)d_in[2];
    const float* pd  = (const float*)d_in[3];
    const int*  sidx = (const int*)d_in[4];
    float* out = (float*)d_out;

    int* hq = (int*)d_ws;
    int* hk = hq + BHS;
    int* qs = hk + BHS;
    int* ks = qs + BHS;
    float* lseblk = (float*)(ks + BHS);
    float* ablk   = lseblk + BHS;

    k_hash<<<BH * NB, 256, 0, stream>>>(q, k, pd, hq, hk);
    k_sort<<<2 * BH, SORT_NT, 0, stream>>>(hq, hk, qs, ks);
    k_blk<<<BH * NB, 256, 0, stream>>>(q, k, v, qs, ks, ablk, lseblk);
    k_res<<<BH * NB, 256, 0, stream>>>(q, k, v, sidx, ablk, lseblk, out);
}

// Round 2
// 329.760 us; speedup vs baseline: 3.8416x; 3.8416x over previous
//
#include <hip/hip_runtime.h>
#include <hip/hip_bf16.h>

#define B 2
#define S 8192
#define H 16
#define D 64
#define NB 32          // S / BS
#define BS 256
#define SAMP 256
#define BH (B*H)
#define BHS (B*H*S)
#define LOG32 3.4657359027997265f   // log(8192/256)

typedef float f32x4 __attribute__((ext_vector_type(4)));
typedef short bf16x8 __attribute__((ext_vector_type(8)));

__device__ __forceinline__ unsigned short f2bf(float x) {
    unsigned int u = __builtin_bit_cast(unsigned int, x);
    u += 0x7fffu + ((u >> 16) & 1u);       // round-to-nearest-even
    return (unsigned short)(u >> 16);
}

// ---------------------------------------------------------------------------
// Kernel 1: LSH hash of Q and K.  hash = gray(bin) = bin ^ (bin>>1)
// ---------------------------------------------------------------------------
__global__ __launch_bounds__(256) void k_hash(const float* __restrict__ q,
                                              const float* __restrict__ k,
                                              const float* __restrict__ pd,
                                              int* __restrict__ hq,
                                              int* __restrict__ hk) {
    __shared__ float spd[D * 8];
    const int t = threadIdx.x;
    for (int i = t; i < D * 8; i += 256) spd[i] = pd[i];
    __syncthreads();

    const int sc = blockIdx.x & (NB - 1);
    const int bh = blockIdx.x >> 5;
    const int s  = sc * 256 + t;
    const int h  = bh & (H - 1), b = bh >> 4;

    const int rowoff = (((b * S + s)) * H + h) * D;
    const float4* q4 = (const float4*)(q + rowoff);
    const float4* k4 = (const float4*)(k + rowoff);

    float dq[8], dk[8];
#pragma unroll
    for (int p = 0; p < 8; ++p) { dq[p] = 0.f; dk[p] = 0.f; }

#pragma unroll
    for (int i = 0; i < 16; ++i) {
        float4 xq = q4[i];
        float4 xk = k4[i];
#pragma unroll
        for (int p = 0; p < 8; ++p) {
            dq[p] += xq.x * spd[(4*i+0)*8+p] + xq.y * spd[(4*i+1)*8+p]
                   + xq.z * spd[(4*i+2)*8+p] + xq.w * spd[(4*i+3)*8+p];
            dk[p] += xk.x * spd[(4*i+0)*8+p] + xk.y * spd[(4*i+1)*8+p]
                   + xk.z * spd[(4*i+2)*8+p] + xk.w * spd[(4*i+3)*8+p];
        }
    }
    int bq = 0, bk = 0;
#pragma unroll
    for (int p = 0; p < 8; ++p) {
        bq |= (dq[p] > 0.f) ? (1 << p) : 0;
        bk |= (dk[p] > 0.f) ? (1 << p) : 0;
    }
    hq[bh * S + s] = bq ^ (bq >> 1);
    hk[bh * S + s] = bk ^ (bk >> 1);
}

// ---------------------------------------------------------------------------
// Kernel 2: stable counting sort (argsort) of hashes per (b,h).
// ---------------------------------------------------------------------------
#define SORT_NT 64
#define SORT_CH (S / SORT_NT)   // 128

__global__ __launch_bounds__(SORT_NT) void k_sort(const int* __restrict__ hq,
                                                  const int* __restrict__ hk,
                                                  int* __restrict__ qs,
                                                  int* __restrict__ ks) {
    __shared__ int hist[SORT_NT * 256];
    __shared__ int base[257];
    const int t  = threadIdx.x;
    const int bh = blockIdx.x & (BH - 1);
    const bool isQ = blockIdx.x < BH;
    const int* hp = (isQ ? hq : hk) + bh * S;
    int*       sp = (isQ ? qs : ks) + bh * S;

    for (int i = 0; i < 256; ++i) hist[t * 256 + i] = 0;
    __syncthreads();
    for (int i = 0; i < SORT_CH; ++i) hist[t * 256 + hp[t * SORT_CH + i]]++;
    __syncthreads();

    for (int bi = 0; bi < 4; ++bi) {
        const int bin = t * 4 + bi;
        int sum = 0;
        for (int tt = 0; tt < SORT_NT; ++tt) sum += hist[tt * 256 + bin];
        base[bin + 1] = sum;
    }
    __syncthreads();
    if (t == 0) {
        base[0] = 0;
        for (int i = 1; i <= 256; ++i) base[i] += base[i - 1];
    }
    __syncthreads();

    for (int bi = 0; bi < 4; ++bi) {
        const int bin = t * 4 + bi;
        int run = base[bin];
        for (int tt = 0; tt < SORT_NT; ++tt) {
            int c = hist[tt * 256 + bin];
            hist[tt * 256 + bin] = run;
            run += c;
        }
    }
    __syncthreads();

    for (int i = 0; i < SORT_CH; ++i) {
        const int s0  = t * SORT_CH + i;
        const int bin = hp[s0];
        sp[hist[t * 256 + bin]++] = s0;
    }
}

// ---------------------------------------------------------------------------
// Kernel 3/4 (templated): MFMA attention over 256 q x 256 k per block.
// RES=0: block-diagonal attention in LSH-sorted order, scatter to original
//        query order (ablk + lseblk).
// RES=1: residual sampled-key attention + logaddexp combine -> out.
// 512 threads = 8 waves; wave w owns queries w*32..w*32+31.
// mfma_f32_16x16x32_bf16 layouts (verified m89/m91):
//   A: row = lane&15, k = (lane>>4)*8 + j     B: col = lane&15, same k
//   C/D: col = lane&15, row = (lane>>4)*4 + reg
// ---------------------------------------------------------------------------
#define VP 264    // vT pitch in ushorts (256 + 8 pad; 528 B rows, 16B aligned)
#define PP 40     // P  pitch in ushorts (32 + 8 pad;  80 B rows, 16B aligned)

template<int RES>
__global__ __launch_bounds__(512) void k_attn(const float* __restrict__ q,
                                              const float* __restrict__ k,
                                              const float* __restrict__ v,
                                              const int* __restrict__ qs,
                                              const int* __restrict__ ks,
                                              const int* __restrict__ sidx,
                                              float* __restrict__ ablk,
                                              float* __restrict__ lseblk,
                                              float* __restrict__ out) {
    __shared__ __align__(16) unsigned short vT[64 * VP];       // V^T bf16
    __shared__ __align__(16) unsigned short pL[8 * 32 * PP];   // per-wave P

    const int t    = threadIdx.x;
    const int w    = t >> 6;
    const int lane = t & 63;
    const int lg   = lane >> 4;      // 0..3
    const int lr   = lane & 15;      // 0..15
    const int blk  = blockIdx.x & (NB - 1);
    const int bh   = blockIdx.x >> 5;
    const int h    = bh & (H - 1), b = bh >> 4;
    const int sbase = bh * S + blk * BS;

    // ---- stage V^T into LDS (2 threads per key row) ----
    {
        const int key  = t >> 1;
        const int d0   = (t & 1) * 32;
        const int krow = RES ? sidx[bh * SAMP + key] : ks[sbase + key];
        const float* vr = v + (((b * S + krow) * H + h) << 6) + d0;
#pragma unroll
        for (int i = 0; i < 8; ++i) {
            float4 x = ((const float4*)vr)[i];
            const int d = d0 + i * 4;
            vT[(d + 0) * VP + key] = f2bf(x.x);
            vT[(d + 1) * VP + key] = f2bf(x.y);
            vT[(d + 2) * VP + key] = f2bf(x.z);
            vT[(d + 3) * VP + key] = f2bf(x.w);
        }
    }

    // ---- Q A-fragments (scale 1/8 folded in) ----
    bf16x8 aq[2][2];
#pragma unroll
    for (int qg = 0; qg < 2; ++qg) {
        const int qi   = w * 32 + qg * 16 + lr;
        const int qrow = RES ? blk * BS + qi : qs[sbase + qi];
        const float* qr = q + (((b * S + qrow) * H + h) << 6) + lg * 8;
#pragma unroll
        for (int kf = 0; kf < 2; ++kf) {
            float4 x0 = ((const float4*)(qr + kf * 32))[0];
            float4 x1 = ((const float4*)(qr + kf * 32))[1];
            union { bf16x8 v8; unsigned short u[8]; } fa;
            fa.u[0] = f2bf(x0.x * 0.125f); fa.u[1] = f2bf(x0.y * 0.125f);
            fa.u[2] = f2bf(x0.z * 0.125f); fa.u[3] = f2bf(x0.w * 0.125f);
            fa.u[4] = f2bf(x1.x * 0.125f); fa.u[5] = f2bf(x1.y * 0.125f);
            fa.u[6] = f2bf(x1.z * 0.125f); fa.u[7] = f2bf(x1.w * 0.125f);
            aq[qg][kf] = fa.v8;
        }
    }
    __syncthreads();   // vT ready

    unsigned short* pw = pL + w * 32 * PP;

    f32x4 acc[2][4];
    float m_run[2][4], l_run[2][4];
#pragma unroll
    for (int qg = 0; qg < 2; ++qg)
#pragma unroll
        for (int dg = 0; dg < 4; ++dg) {
            acc[qg][dg] = (f32x4){0.f, 0.f, 0.f, 0.f};
        }
#pragma unroll
    for (int qg = 0; qg < 2; ++qg)
#pragma unroll
        for (int r = 0; r < 4; ++r) { m_run[qg][r] = -1e30f; l_run[qg][r] = 0.f; }

    for (int kt = 0; kt < 4; ++kt) {
        // ---- K B-fragments (direct global, inline cvt) ----
        bf16x8 bk[4][2];
#pragma unroll
        for (int kg = 0; kg < 4; ++kg) {
            const int ki   = kt * 64 + kg * 16 + lr;
            const int krow = RES ? sidx[bh * SAMP + ki] : ks[sbase + ki];
            const float* kr = k + (((b * S + krow) * H + h) << 6) + lg * 8;
#pragma unroll
            for (int kf = 0; kf < 2; ++kf) {
                float4 x0 = ((const float4*)(kr + kf * 32))[0];
                float4 x1 = ((const float4*)(kr + kf * 32))[1];
                union { bf16x8 v8; unsigned short u[8]; } fb;
                fb.u[0] = f2bf(x0.x); fb.u[1] = f2bf(x0.y);
                fb.u[2] = f2bf(x0.z); fb.u[3] = f2bf(x0.w);
                fb.u[4] = f2bf(x1.x); fb.u[5] = f2bf(x1.y);
                fb.u[6] = f2bf(x1.z); fb.u[7] = f2bf(x1.w);
                bk[kg][kf] = fb.v8;
            }
        }

        // ---- S = (Q/8) K^T ----
        f32x4 c[2][4];
#pragma unroll
        for (int qg = 0; qg < 2; ++qg)
#pragma unroll
            for (int kg = 0; kg < 4; ++kg) {
                f32x4 z = (f32x4){0.f, 0.f, 0.f, 0.f};
                z = __builtin_amdgcn_mfma_f32_16x16x32_bf16(aq[qg][0], bk[kg][0], z, 0, 0, 0);
                c[qg][kg] = __builtin_amdgcn_mfma_f32_16x16x32_bf16(aq[qg][1], bk[kg][1], z, 0, 0, 0);
            }

        // ---- online softmax (rows live in lanes lr of each fragment col) ----
        float esc[2][4];
#pragma unroll
        for (int qg = 0; qg < 2; ++qg) {
#pragma unroll
            for (int r = 0; r < 4; ++r) {
                float tm = fmaxf(fmaxf(c[qg][0][r], c[qg][1][r]),
                                 fmaxf(c[qg][2][r], c[qg][3][r]));
                tm = fmaxf(tm, __shfl_xor(tm, 1));
                tm = fmaxf(tm, __shfl_xor(tm, 2));
                tm = fmaxf(tm, __shfl_xor(tm, 4));
                tm = fmaxf(tm, __shfl_xor(tm, 8));
                const float mn = fmaxf(m_run[qg][r], tm);
                esc[qg][r] = __expf(m_run[qg][r] - mn);
                m_run[qg][r] = mn;
                float rs = 0.f;
#pragma unroll
                for (int kg = 0; kg < 4; ++kg) {
                    const float p = __expf(c[qg][kg][r] - mn);
                    c[qg][kg][r] = p;
                    rs += p;
                }
                rs += __shfl_xor(rs, 1);
                rs += __shfl_xor(rs, 2);
                rs += __shfl_xor(rs, 4);
                rs += __shfl_xor(rs, 8);
                l_run[qg][r] = l_run[qg][r] * esc[qg][r] + rs;
#pragma unroll
                for (int dg = 0; dg < 4; ++dg) acc[qg][dg][r] *= esc[qg][r];
            }
        }

        // ---- PV in two 32-key halves (P via per-wave LDS transpose) ----
#pragma unroll
        for (int hh = 0; hh < 2; ++hh) {
#pragma unroll
            for (int qg = 0; qg < 2; ++qg)
#pragma unroll
                for (int kg2 = 0; kg2 < 2; ++kg2) {
                    const int kg = hh * 2 + kg2;
#pragma unroll
                    for (int r = 0; r < 4; ++r)
                        pw[(qg * 16 + lg * 4 + r) * PP + kg2 * 16 + lr] = f2bf(c[qg][kg][r]);
                }
            bf16x8 ap[2], bv[4];
#pragma unroll
            for (int qg = 0; qg < 2; ++qg)
                ap[qg] = *(const bf16x8*)&pw[(qg * 16 + lr) * PP + lg * 8];
#pragma unroll
            for (int dg = 0; dg < 4; ++dg)
                bv[dg] = *(const bf16x8*)&vT[(dg * 16 + lr) * VP + kt * 64 + hh * 32 + lg * 8];
#pragma unroll
            for (int qg = 0; qg < 2; ++qg)
#pragma unroll
                for (int dg = 0; dg < 4; ++dg)
                    acc[qg][dg] = __builtin_amdgcn_mfma_f32_16x16x32_bf16(ap[qg], bv[dg], acc[qg][dg], 0, 0, 0);
        }
    }

    // ---- epilogue ----
#pragma unroll
    for (int qg = 0; qg < 2; ++qg) {
#pragma unroll
        for (int r = 0; r < 4; ++r) {
            const int qi   = w * 32 + qg * 16 + lg * 4 + r;
            const int qrow = RES ? blk * BS + qi : qs[sbase + qi];
            const float inv = 1.f / l_run[qg][r];
            const float lse = m_run[qg][r] + __logf(l_run[qg][r]);
            const int obase = ((b * S + qrow) * H + h) << 6;
            if (!RES) {
#pragma unroll
                for (int dg = 0; dg < 4; ++dg)
                    ablk[obase + dg * 16 + lr] = acc[qg][dg][r] * inv;
                if (lr == 0) lseblk[(b * S + qrow) * H + h] = lse;
            } else {
                const float lb  = lseblk[(b * S + qrow) * H + h];
                const float lrr = lse + LOG32;
                const float mx  = fmaxf(lb, lrr);
                const float lt  = mx + __logf(__expf(lb - mx) + __expf(lrr - mx));
                const float wb  = __expf(lb - lt);
                const float wr  = __expf(lrr - lt) * inv;
#pragma unroll
                for (int dg = 0; dg < 4; ++dg)
                    out[obase + dg * 16 + lr] = ablk[obase + dg * 16 + lr] * wb
                                              + acc[qg][dg][r] * wr;
            }
        }
    }
}

// ---------------------------------------------------------------------------
extern "C" void kernel_launch(void* const* d_in, const int* in_sizes, int n_in,
                              void* d_out, int out_size, void* d_ws, size_t ws_size,
                              hipStream_t stream) {
    const float* q   = (const float*)d_in[0];
    const float* k   = (const float*)d_in[1];
    const float* v   = (const float*)d_in[2];
    const float* pd  = (const float*)d_in[3];
    const int*  sidx = (const int*)d_in[4];
    float* out = (float*)d_out;

    int* hq = (int*)d_ws;
    int* hk = hq + BHS;
    int* qs = hk + BHS;
    int* ks = qs + BHS;
    float* lseblk = (float*)(ks + BHS);
    float* ablk   = lseblk + BHS;

    k_hash<<<BH * NB, 256, 0, stream>>>(q, k, pd, hq, hk);
    k_sort<<<2 * BH, SORT_NT, 0, stream>>>(hq, hk, qs, ks);
    k_attn<0><<<BH * NB, 512, 0, stream>>>(q, k, v, qs, ks, sidx, ablk, lseblk, out);
    k_attn<1><<<BH * NB, 512, 0, stream>>>(q, k, v, qs, ks, sidx, ablk, lseblk, out);
}

// Round 3
// 230.384 us; speedup vs baseline: 5.4986x; 1.4313x over previous
//
#include <hip/hip_runtime.h>
#include <hip/hip_bf16.h>

#define B 2
#define S 8192
#define H 16
#define D 64
#define NB 32          // S / BS
#define BS 256
#define SAMP 256
#define BH (B*H)
#define BHS (B*H*S)
#define BSHD (B*S*H*D)
#define LOG32 3.4657359027997265f   // log(8192/256)

typedef float f32x4 __attribute__((ext_vector_type(4)));
typedef short bf16x8 __attribute__((ext_vector_type(8)));

__device__ __forceinline__ unsigned short f2bf(float x) {
    unsigned int u = __builtin_bit_cast(unsigned int, x);
    u += 0x7fffu + ((u >> 16) & 1u);       // round-to-nearest-even
    return (unsigned short)(u >> 16);
}
__device__ __forceinline__ unsigned int pack2(float a, float b) {
    return (unsigned int)f2bf(a) | ((unsigned int)f2bf(b) << 16);
}

// ---------------------------------------------------------------------------
// Kernel 1: LSH hash of Q and K  +  bf16 pre-conversion of Q(*0.125)/K/V.
// hash = gray(bin) = bin ^ (bin>>1).  grid BH*NB x 256, thread = one row.
// ---------------------------------------------------------------------------
__global__ __launch_bounds__(256) void k_prep(const float* __restrict__ q,
                                              const float* __restrict__ k,
                                              const float* __restrict__ v,
                                              const float* __restrict__ pd,
                                              int* __restrict__ hq,
                                              int* __restrict__ hk,
                                              unsigned short* __restrict__ qbf,
                                              unsigned short* __restrict__ kbf,
                                              unsigned short* __restrict__ vbf) {
    __shared__ float spd[D * 8];
    const int t = threadIdx.x;
    for (int i = t; i < D * 8; i += 256) spd[i] = pd[i];
    __syncthreads();

    const int sc = blockIdx.x & (NB - 1);
    const int bh = blockIdx.x >> 5;
    const int s  = sc * 256 + t;
    const int h  = bh & (H - 1), b = bh >> 4;
    const int base = ((b * S + s) * H + h) << 6;

    float dq[8], dk[8];
#pragma unroll
    for (int p = 0; p < 8; ++p) { dq[p] = 0.f; dk[p] = 0.f; }

#pragma unroll
    for (int i = 0; i < 8; ++i) {           // 8 floats per iter
        float4 x0 = ((const float4*)(q + base + i * 8))[0];
        float4 x1 = ((const float4*)(q + base + i * 8))[1];
        float4 y0 = ((const float4*)(k + base + i * 8))[0];
        float4 y1 = ((const float4*)(k + base + i * 8))[1];
#pragma unroll
        for (int p = 0; p < 8; ++p) {
            dq[p] += x0.x * spd[(8*i+0)*8+p] + x0.y * spd[(8*i+1)*8+p]
                   + x0.z * spd[(8*i+2)*8+p] + x0.w * spd[(8*i+3)*8+p]
                   + x1.x * spd[(8*i+4)*8+p] + x1.y * spd[(8*i+5)*8+p]
                   + x1.z * spd[(8*i+6)*8+p] + x1.w * spd[(8*i+7)*8+p];
            dk[p] += y0.x * spd[(8*i+0)*8+p] + y0.y * spd[(8*i+1)*8+p]
                   + y0.z * spd[(8*i+2)*8+p] + y0.w * spd[(8*i+3)*8+p]
                   + y1.x * spd[(8*i+4)*8+p] + y1.y * spd[(8*i+5)*8+p]
                   + y1.z * spd[(8*i+6)*8+p] + y1.w * spd[(8*i+7)*8+p];
        }
        uint4 uq, uk;
        uq.x = pack2(x0.x * 0.125f, x0.y * 0.125f);
        uq.y = pack2(x0.z * 0.125f, x0.w * 0.125f);
        uq.z = pack2(x1.x * 0.125f, x1.y * 0.125f);
        uq.w = pack2(x1.z * 0.125f, x1.w * 0.125f);
        uk.x = pack2(y0.x, y0.y); uk.y = pack2(y0.z, y0.w);
        uk.z = pack2(y1.x, y1.y); uk.w = pack2(y1.z, y1.w);
        *(uint4*)(qbf + base + i * 8) = uq;
        *(uint4*)(kbf + base + i * 8) = uk;

        float4 z0 = ((const float4*)(v + base + i * 8))[0];
        float4 z1 = ((const float4*)(v + base + i * 8))[1];
        uint4 uv;
        uv.x = pack2(z0.x, z0.y); uv.y = pack2(z0.z, z0.w);
        uv.z = pack2(z1.x, z1.y); uv.w = pack2(z1.z, z1.w);
        *(uint4*)(vbf + base + i * 8) = uv;
    }
    int bq = 0, bk = 0;
#pragma unroll
    for (int p = 0; p < 8; ++p) {
        bq |= (dq[p] > 0.f) ? (1 << p) : 0;
        bk |= (dk[p] > 0.f) ? (1 << p) : 0;
    }
    hq[bh * S + s] = bq ^ (bq >> 1);
    hk[bh * S + s] = bk ^ (bk >> 1);
}

// ---------------------------------------------------------------------------
// Kernel 2: stable counting sort (argsort) of hashes per (b,h).  (unchanged)
// ---------------------------------------------------------------------------
#define SORT_NT 64
#define SORT_CH (S / SORT_NT)   // 128

__global__ __launch_bounds__(SORT_NT) void k_sort(const int* __restrict__ hq,
                                                  const int* __restrict__ hk,
                                                  int* __restrict__ qs,
                                                  int* __restrict__ ks) {
    __shared__ int hist[SORT_NT * 256];
    __shared__ int base[257];
    const int t  = threadIdx.x;
    const int bh = blockIdx.x & (BH - 1);
    const bool isQ = blockIdx.x < BH;
    const int* hp = (isQ ? hq : hk) + bh * S;
    int*       sp = (isQ ? qs : ks) + bh * S;

    for (int i = 0; i < 256; ++i) hist[t * 256 + i] = 0;
    __syncthreads();
    for (int i = 0; i < SORT_CH; ++i) hist[t * 256 + hp[t * SORT_CH + i]]++;
    __syncthreads();

    for (int bi = 0; bi < 4; ++bi) {
        const int bin = t * 4 + bi;
        int sum = 0;
        for (int tt = 0; tt < SORT_NT; ++tt) sum += hist[tt * 256 + bin];
        base[bin + 1] = sum;
    }
    __syncthreads();
    if (t == 0) {
        base[0] = 0;
        for (int i = 1; i <= 256; ++i) base[i] += base[i - 1];
    }
    __syncthreads();

    for (int bi = 0; bi < 4; ++bi) {
        const int bin = t * 4 + bi;
        int run = base[bin];
        for (int tt = 0; tt < SORT_NT; ++tt) {
            int c = hist[tt * 256 + bin];
            hist[tt * 256 + bin] = run;
            run += c;
        }
    }
    __syncthreads();

    for (int i = 0; i < SORT_CH; ++i) {
        const int s0  = t * SORT_CH + i;
        const int bin = hp[s0];
        sp[hist[t * 256 + bin]++] = s0;
    }
}

// ---------------------------------------------------------------------------
// Kernel 3: FUSED attention.  One online softmax over 512 keys:
//   pass 0 = 256 LSH-block keys, pass 1 = 256 sampled keys (scores + LOG32).
// Swapped QK^T:  c = mfma(A=K, B=Q)  ->  lane(lg,lr) holds
//   P[query=qg*16+lr][key=kg*16+lg*4+r]  (keys in-lane => cheap row reduce,
//   4 consecutive keys per fragment reg => packed b64 P-writes).
// PV: A=P (row=query), B=V^T (col=d).  acc row = query qg*16+lg*4+r, col=d.
// out = acc / l  (running max cancels).  512 thr = 8 waves x 32 queries.
// ---------------------------------------------------------------------------
#define VP 264    // vT pitch (256 + 8 pad)
#define PP 40     // per-wave P pitch (32 + 8 pad)

__global__ __launch_bounds__(512, 4) void k_attn(const unsigned short* __restrict__ qbf,
                                                 const unsigned short* __restrict__ kbf,
                                                 const unsigned short* __restrict__ vbf,
                                                 const int* __restrict__ qs,
                                                 const int* __restrict__ ks,
                                                 const int* __restrict__ sidx,
                                                 float* __restrict__ out) {
    __shared__ __align__(16) unsigned short vT[64 * VP];
    __shared__ __align__(16) unsigned short pL[8 * 32 * PP];

    const int t    = threadIdx.x;
    const int w    = t >> 6;
    const int lane = t & 63;
    const int lg   = lane >> 4;      // 0..3
    const int lr   = lane & 15;      // 0..15
    const int blk  = blockIdx.x & (NB - 1);
    const int bh   = blockIdx.x >> 5;
    const int h    = bh & (H - 1), b = bh >> 4;
    const int sbase = bh * S + blk * BS;
    unsigned short* pw = pL + w * 32 * PP;

    // ---- Q B-fragments (pre-scaled bf16) + query rows ----
    int qrow[2]; bf16x8 bq[2][2];
#pragma unroll
    for (int qg = 0; qg < 2; ++qg) {
        qrow[qg] = qs[sbase + w * 32 + qg * 16 + lr];
        const unsigned short* qp = qbf + (((b * S + qrow[qg]) * H + h) << 6);
        bq[qg][0] = *(const bf16x8*)(qp + lg * 8);
        bq[qg][1] = *(const bf16x8*)(qp + 32 + lg * 8);
    }

    float m_run[2] = {-1e30f, -1e30f}, l_run[2] = {0.f, 0.f};
    f32x4 acc[2][4];
#pragma unroll
    for (int qg = 0; qg < 2; ++qg)
#pragma unroll
        for (int dg = 0; dg < 4; ++dg) acc[qg][dg] = (f32x4){0.f, 0.f, 0.f, 0.f};

    for (int pass = 0; pass < 2; ++pass) {
        if (pass) __syncthreads();              // all reads of old vT done
        {   // ---- stage V^T (bf16, scalar transpose scatter) ----
            const int key = t >> 1, d0 = (t & 1) * 32;
            const int krow = pass ? sidx[bh * SAMP + key] : ks[sbase + key];
            const unsigned short* vp = vbf + (((b * S + krow) * H + h) << 6) + d0;
#pragma unroll
            for (int i = 0; i < 4; ++i) {
                uint4 x = *(const uint4*)(vp + i * 8);
                const int d = d0 + i * 8;
                vT[(d + 0) * VP + key] = (unsigned short)(x.x);
                vT[(d + 1) * VP + key] = (unsigned short)(x.x >> 16);
                vT[(d + 2) * VP + key] = (unsigned short)(x.y);
                vT[(d + 3) * VP + key] = (unsigned short)(x.y >> 16);
                vT[(d + 4) * VP + key] = (unsigned short)(x.z);
                vT[(d + 5) * VP + key] = (unsigned short)(x.z >> 16);
                vT[(d + 6) * VP + key] = (unsigned short)(x.w);
                vT[(d + 7) * VP + key] = (unsigned short)(x.w >> 16);
            }
        }
        __syncthreads();

        const float bias = pass ? LOG32 : 0.f;
        for (int kt4 = 0; kt4 < 4; ++kt4) {
            // ---- gathered key rows ----
            int krw[4];
#pragma unroll
            for (int kg = 0; kg < 4; ++kg) {
                const int key = kt4 * 64 + kg * 16 + lr;
                krw[kg] = pass ? sidx[bh * SAMP + key] : ks[sbase + key];
            }
            // ---- S^T = K Q^T  (A=K frags, B=Q frags) ----
            f32x4 c[2][4];
#pragma unroll
            for (int kf = 0; kf < 2; ++kf) {
                bf16x8 ak[4];
#pragma unroll
                for (int kg = 0; kg < 4; ++kg)
                    ak[kg] = *(const bf16x8*)(kbf + (((b * S + krw[kg]) * H + h) << 6)
                                              + kf * 32 + lg * 8);
#pragma unroll
                for (int qg = 0; qg < 2; ++qg)
#pragma unroll
                    for (int kg = 0; kg < 4; ++kg) {
                        f32x4 cin = kf ? c[qg][kg] : (f32x4){0.f, 0.f, 0.f, 0.f};
                        c[qg][kg] = __builtin_amdgcn_mfma_f32_16x16x32_bf16(ak[kg], bq[qg][kf], cin, 0, 0, 0);
                    }
            }
            // ---- online softmax: keys mostly in-lane ----
            float esc[2];
#pragma unroll
            for (int qg = 0; qg < 2; ++qg) {
                float tm = -1e30f;
#pragma unroll
                for (int kg = 0; kg < 4; ++kg)
#pragma unroll
                    for (int r = 0; r < 4; ++r) tm = fmaxf(tm, c[qg][kg][r]);
                tm = fmaxf(tm, __shfl_xor(tm, 16));
                tm = fmaxf(tm, __shfl_xor(tm, 32));
                tm += bias;
                const float mn = fmaxf(m_run[qg], tm);
                esc[qg] = __expf(m_run[qg] - mn);
                m_run[qg] = mn;
                const float mnb = mn - bias;
                float rs = 0.f;
#pragma unroll
                for (int kg = 0; kg < 4; ++kg)
#pragma unroll
                    for (int r = 0; r < 4; ++r) {
                        const float p = __expf(c[qg][kg][r] - mnb);
                        c[qg][kg][r] = p;
                        rs += p;
                    }
                rs += __shfl_xor(rs, 16);
                rs += __shfl_xor(rs, 32);
                l_run[qg] = l_run[qg] * esc[qg] + rs;
            }
            // ---- rescale acc (esc lives per query=lr; acc rows = lg*4+r) ----
#pragma unroll
            for (int qg = 0; qg < 2; ++qg)
#pragma unroll
                for (int r = 0; r < 4; ++r) {
                    const float er = __shfl(esc[qg], lg * 4 + r);
#pragma unroll
                    for (int dg = 0; dg < 4; ++dg) acc[qg][dg][r] *= er;
                }
            // ---- PV in 32-key halves: packed P write, b128 reads ----
#pragma unroll
            for (int hh = 0; hh < 2; ++hh) {
#pragma unroll
                for (int qg = 0; qg < 2; ++qg)
#pragma unroll
                    for (int kg2 = 0; kg2 < 2; ++kg2) {
                        const int kg = hh * 2 + kg2;
                        uint2 u;
                        u.x = pack2(c[qg][kg][0], c[qg][kg][1]);
                        u.y = pack2(c[qg][kg][2], c[qg][kg][3]);
                        *(uint2*)&pw[(qg * 16 + lr) * PP + kg2 * 16 + lg * 4] = u;
                    }
                bf16x8 bv[4];
#pragma unroll
                for (int dg = 0; dg < 4; ++dg)
                    bv[dg] = *(const bf16x8*)&vT[(dg * 16 + lr) * VP + kt4 * 64 + hh * 32 + lg * 8];
#pragma unroll
                for (int qg = 0; qg < 2; ++qg) {
                    const bf16x8 ap = *(const bf16x8*)&pw[(qg * 16 + lr) * PP + lg * 8];
#pragma unroll
                    for (int dg = 0; dg < 4; ++dg)
                        acc[qg][dg] = __builtin_amdgcn_mfma_f32_16x16x32_bf16(ap, bv[dg], acc[qg][dg], 0, 0, 0);
                }
            }
        }
    }

    // ---- epilogue: out = acc / l, scattered to original query order ----
#pragma unroll
    for (int qg = 0; qg < 2; ++qg)
#pragma unroll
        for (int r = 0; r < 4; ++r) {
            const float lq = __shfl(l_run[qg], lg * 4 + r);
            const int   qr = __shfl(qrow[qg], lg * 4 + r);
            const float inv = 1.f / lq;
            const int obase = ((b * S + qr) * H + h) << 6;
#pragma unroll
            for (int dg = 0; dg < 4; ++dg)
                out[obase + dg * 16 + lr] = acc[qg][dg][r] * inv;
        }
}

// ---------------------------------------------------------------------------
extern "C" void kernel_launch(void* const* d_in, const int* in_sizes, int n_in,
                              void* d_out, int out_size, void* d_ws, size_t ws_size,
                              hipStream_t stream) {
    const float* q   = (const float*)d_in[0];
    const float* k   = (const float*)d_in[1];
    const float* v   = (const float*)d_in[2];
    const float* pd  = (const float*)d_in[3];
    const int*  sidx = (const int*)d_in[4];
    float* out = (float*)d_out;

    int* hq = (int*)d_ws;
    int* hk = hq + BHS;
    int* qs = hk + BHS;
    int* ks = qs + BHS;
    unsigned short* qbf = (unsigned short*)(ks + BHS);
    unsigned short* kbf = qbf + BSHD;
    unsigned short* vbf = kbf + BSHD;

    k_prep<<<BH * NB, 256, 0, stream>>>(q, k, v, pd, hq, hk, qbf, kbf, vbf);
    k_sort<<<2 * BH, SORT_NT, 0, stream>>>(hq, hk, qs, ks);
    k_attn<<<BH * NB, 512, 0, stream>>>(qbf, kbf, vbf, qs, ks, sidx, out);
}